// Round 1
// baseline (264.087 us; speedup 1.0000x reference)
//
#include <hip/hip_runtime.h>

#define NL 3
#define NB 32768
#define ND 1024
#define NHK 512

// t[i][j] = sum_d wo[i][j][d] * cw[i][d]        (wo: [L][HK][D], cw: [L][D])
__global__ __launch_bounds__(256) void precompute_t(const float* __restrict__ wo,
                                                    const float* __restrict__ cw,
                                                    float* __restrict__ t) {
    int wave = (blockIdx.x * blockDim.x + threadIdx.x) >> 6;
    int lane = threadIdx.x & 63;
    if (wave >= NL * NHK) return;
    int i = wave >> 9;  // wave = i*512 + j
    const float* worow = wo + (size_t)wave * ND;
    const float* cwrow = cw + (size_t)i * ND;
    float acc = 0.f;
#pragma unroll
    for (int r = 0; r < ND / 64; ++r) {
        int d = r * 64 + lane;
        acc += worow[d] * cwrow[d];
    }
#pragma unroll
    for (int m = 32; m; m >>= 1) acc += __shfl_xor(acc, m);
    if (lane == 0) t[wave] = acc;
}

// U[d] = sum_i sum_j wv[i][d][j] * t[i][j]      (wv: [L][D][HK])
__global__ __launch_bounds__(256) void precompute_U(const float* __restrict__ wv,
                                                    const float* __restrict__ t,
                                                    float* __restrict__ U) {
    int d = (blockIdx.x * blockDim.x + threadIdx.x) >> 6;
    int lane = threadIdx.x & 63;
    if (d >= ND) return;
    float acc = 0.f;
    for (int i = 0; i < NL; ++i) {
        const float* wvrow = wv + ((size_t)i * ND + d) * NHK;
        const float* ti = t + i * NHK;
#pragma unroll
        for (int r = 0; r < NHK / 64; ++r) {
            int j = r * 64 + lane;
            acc += wvrow[j] * ti[j];
        }
    }
#pragma unroll
    for (int m = 32; m; m >>= 1) acc += __shfl_xor(acc, m);
    if (lane == 0) U[d] = acc;
}

// cbsum[d] = sum_i cb[i][d];  C = sum_i (bv[i]·t[i] + bo[i]·cw[i])
__global__ __launch_bounds__(1024) void precompute_scalar(const float* __restrict__ bv,
                                                          const float* __restrict__ bo,
                                                          const float* __restrict__ cw,
                                                          const float* __restrict__ cb,
                                                          const float* __restrict__ t,
                                                          float* __restrict__ cbsum,
                                                          float* __restrict__ Cout) {
    int tid = threadIdx.x;
    cbsum[tid] = cb[tid] + cb[ND + tid] + cb[2 * ND + tid];
    float p = 0.f;
    for (int idx = tid; idx < NL * NHK; idx += 1024) p += bv[idx] * t[idx];
    for (int idx = tid; idx < NL * ND; idx += 1024) p += bo[idx] * cw[idx];
    __shared__ float red[1024];
    red[tid] = p;
    __syncthreads();
    for (int s = 512; s > 0; s >>= 1) {
        if (tid < s) red[tid] += red[tid + s];
        __syncthreads();
    }
    if (tid == 0) Cout[0] = red[0];
}

// out[b,d] = x[b,d] * (1 + C + x[b,:]·U) + cbsum[d]
__global__ __launch_bounds__(256) void fused_main(const float* __restrict__ x,
                                                  const float* __restrict__ U,
                                                  const float* __restrict__ cbsum,
                                                  const float* __restrict__ Cp,
                                                  float* __restrict__ out) {
    int row = (blockIdx.x * 256 + threadIdx.x) >> 6;
    int lane = threadIdx.x & 63;
    const float4* xr = (const float4*)(x + (size_t)row * ND);
    const float4* Ur = (const float4*)U;
    float4 xv[4], uv[4];
    float dot = 0.f;
#pragma unroll
    for (int r = 0; r < 4; ++r) {
        int idx = r * 64 + lane;
        xv[r] = xr[idx];
        uv[r] = Ur[idx];
        dot += xv[r].x * uv[r].x + xv[r].y * uv[r].y + xv[r].z * uv[r].z + xv[r].w * uv[r].w;
    }
#pragma unroll
    for (int m = 32; m; m >>= 1) dot += __shfl_xor(dot, m);
    float s = 1.0f + Cp[0] + dot;
    const float4* cbr = (const float4*)cbsum;
    float4* outr = (float4*)(out + (size_t)row * ND);
#pragma unroll
    for (int r = 0; r < 4; ++r) {
        int idx = r * 64 + lane;
        float4 cbv = cbr[idx];
        float4 o;
        o.x = xv[r].x * s + cbv.x;
        o.y = xv[r].y * s + cbv.y;
        o.z = xv[r].z * s + cbv.z;
        o.w = xv[r].w * s + cbv.w;
        outr[idx] = o;
    }
}

extern "C" void kernel_launch(void* const* d_in, const int* in_sizes, int n_in,
                              void* d_out, int out_size, void* d_ws, size_t ws_size,
                              hipStream_t stream) {
    const float* x  = (const float*)d_in[0];
    const float* wv = (const float*)d_in[5];
    const float* bv = (const float*)d_in[6];
    const float* wo = (const float*)d_in[7];
    const float* bo = (const float*)d_in[8];
    const float* cw = (const float*)d_in[9];
    const float* cb = (const float*)d_in[10];
    float* out = (float*)d_out;

    float* ws    = (float*)d_ws;
    float* t     = ws;          // NL*NHK = 1536 floats
    float* U     = ws + 1536;   // 1024 floats (6144 B offset: 16B-aligned)
    float* cbsum = ws + 2560;   // 1024 floats
    float* Cp    = ws + 3584;   // 1 float

    precompute_t<<<(NL * NHK * 64) / 256, 256, 0, stream>>>(wo, cw, t);
    precompute_U<<<(ND * 64) / 256, 256, 0, stream>>>(wv, t, U);
    precompute_scalar<<<1, 1024, 0, stream>>>(bv, bo, cw, cb, t, cbsum, Cp);
    fused_main<<<(NB * 64) / 256, 256, 0, stream>>>(x, U, cbsum, Cp, out);
}

// Round 5
// 263.419 us; speedup vs baseline: 1.0025x; 1.0025x over previous
//
#include <hip/hip_runtime.h>

#define NL 3
#define NB 32768
#define ND 1024
#define NHK 512

typedef float f32x4 __attribute__((ext_vector_type(4)));

// Kernel A: t[i][j] = wo[i][j][:] . cw[i][:]   (wo: [L][HK][D], cw: [L][D])
// one wave per (i,j); float4 loads.
__global__ __launch_bounds__(256) void k_t(const float* __restrict__ wo,
                                           const float* __restrict__ cw,
                                           float* __restrict__ t) {
    int wave = (blockIdx.x * 256 + threadIdx.x) >> 6;
    int lane = threadIdx.x & 63;
    int i = wave >> 9;  // wave = i*512 + j
    const f32x4* worow = (const f32x4*)(wo + (size_t)wave * ND);
    const f32x4* cwrow = (const f32x4*)(cw + (size_t)i * ND);
    float acc = 0.f;
#pragma unroll
    for (int r = 0; r < ND / 256; ++r) {  // 4 iters of float4
        int idx = r * 64 + lane;
        f32x4 a = worow[idx], b = cwrow[idx];
        acc += a.x * b.x + a.y * b.y + a.z * b.z + a.w * b.w;
    }
#pragma unroll
    for (int m = 32; m; m >>= 1) acc += __shfl_xor(acc, m);
    if (lane == 0) t[wave] = acc;
}

// Kernel B: blocks 0..255  -> U[d] = sum_i wv[i][d][:] . t[i][:]   (one wave per d)
//           block  256     -> cbsum[d] = sum_i cb[i][d]
//           block  257     -> C = sum_i (bv[i].t[i] + bo[i].cw[i])
__global__ __launch_bounds__(256) void k_u(const float* __restrict__ wv,
                                           const float* __restrict__ bv,
                                           const float* __restrict__ bo,
                                           const float* __restrict__ cw,
                                           const float* __restrict__ cb,
                                           const float* __restrict__ t,
                                           float* __restrict__ U,
                                           float* __restrict__ cbsum,
                                           float* __restrict__ Cout) {
    int b = blockIdx.x;
    int tid = threadIdx.x;
    if (b < 256) {
        int d = (b * 256 + tid) >> 6;
        int lane = tid & 63;
        float acc = 0.f;
#pragma unroll
        for (int i = 0; i < NL; ++i) {
            const f32x4* wvrow = (const f32x4*)(wv + ((size_t)i * ND + d) * NHK);
            const f32x4* ti = (const f32x4*)(t + i * NHK);
#pragma unroll
            for (int r = 0; r < NHK / 256; ++r) {  // 2 iters of float4
                int idx = r * 64 + lane;
                f32x4 a = wvrow[idx], c = ti[idx];
                acc += a.x * c.x + a.y * c.y + a.z * c.z + a.w * c.w;
            }
        }
#pragma unroll
        for (int m = 32; m; m >>= 1) acc += __shfl_xor(acc, m);
        if (lane == 0) U[d] = acc;
    } else if (b == 256) {
#pragma unroll
        for (int r = 0; r < 4; ++r) {
            int d = r * 256 + tid;
            cbsum[d] = cb[d] + cb[ND + d] + cb[2 * ND + d];
        }
    } else {
        float p = 0.f;
        for (int idx = tid; idx < NL * NHK; idx += 256) p += bv[idx] * t[idx];
        for (int idx = tid; idx < NL * ND; idx += 256) p += bo[idx] * cw[idx];
        __shared__ float red[256];
        red[tid] = p;
        __syncthreads();
        for (int s = 128; s > 0; s >>= 1) {
            if (tid < s) red[tid] += red[tid + s];
            __syncthreads();
        }
        if (tid == 0) Cout[0] = red[0];
    }
}

// out[b,d] = x[b,d] * (1 + C + x[b,:].U) + cbsum[d]   -- 2 rows per wave
__global__ __launch_bounds__(256) void fused_main(const float* __restrict__ x,
                                                  const float* __restrict__ U,
                                                  const float* __restrict__ cbsum,
                                                  const float* __restrict__ Cp,
                                                  float* __restrict__ out) {
    int wave = (blockIdx.x * 256 + threadIdx.x) >> 6;
    int lane = threadIdx.x & 63;
    size_t row0 = (size_t)wave * 2;
    const f32x4* xr0 = (const f32x4*)(x + row0 * ND);
    const f32x4* xr1 = (const f32x4*)(x + (row0 + 1) * ND);
    const f32x4* Ur = (const f32x4*)U;
    f32x4 a0[4], a1[4], uv[4];
    float d0 = 0.f, d1 = 0.f;
#pragma unroll
    for (int r = 0; r < 4; ++r) {
        int idx = r * 64 + lane;
        a0[r] = __builtin_nontemporal_load(&xr0[idx]);
        a1[r] = __builtin_nontemporal_load(&xr1[idx]);
        uv[r] = Ur[idx];
        d0 += a0[r].x * uv[r].x + a0[r].y * uv[r].y + a0[r].z * uv[r].z + a0[r].w * uv[r].w;
        d1 += a1[r].x * uv[r].x + a1[r].y * uv[r].y + a1[r].z * uv[r].z + a1[r].w * uv[r].w;
    }
#pragma unroll
    for (int m = 32; m; m >>= 1) {
        d0 += __shfl_xor(d0, m);
        d1 += __shfl_xor(d1, m);
    }
    float base = 1.0f + Cp[0];
    float s0 = base + d0;
    float s1 = base + d1;
    const f32x4* cbr = (const f32x4*)cbsum;
    f32x4* outr0 = (f32x4*)(out + row0 * ND);
    f32x4* outr1 = (f32x4*)(out + (row0 + 1) * ND);
#pragma unroll
    for (int r = 0; r < 4; ++r) {
        int idx = r * 64 + lane;
        f32x4 cbv = cbr[idx];
        f32x4 o0, o1;
        o0.x = a0[r].x * s0 + cbv.x;  o0.y = a0[r].y * s0 + cbv.y;
        o0.z = a0[r].z * s0 + cbv.z;  o0.w = a0[r].w * s0 + cbv.w;
        o1.x = a1[r].x * s1 + cbv.x;  o1.y = a1[r].y * s1 + cbv.y;
        o1.z = a1[r].z * s1 + cbv.z;  o1.w = a1[r].w * s1 + cbv.w;
        __builtin_nontemporal_store(o0, &outr0[idx]);
        __builtin_nontemporal_store(o1, &outr1[idx]);
    }
}

extern "C" void kernel_launch(void* const* d_in, const int* in_sizes, int n_in,
                              void* d_out, int out_size, void* d_ws, size_t ws_size,
                              hipStream_t stream) {
    const float* x  = (const float*)d_in[0];
    const float* wv = (const float*)d_in[5];
    const float* bv = (const float*)d_in[6];
    const float* wo = (const float*)d_in[7];
    const float* bo = (const float*)d_in[8];
    const float* cw = (const float*)d_in[9];
    const float* cb = (const float*)d_in[10];
    float* out = (float*)d_out;

    float* ws    = (float*)d_ws;
    float* t     = ws;          // NL*NHK = 1536 floats
    float* U     = ws + 1536;   // 1024 floats (16B-aligned offset)
    float* cbsum = ws + 2560;   // 1024 floats
    float* Cp    = ws + 3584;   // 1 float

    k_t<<<(NL * NHK * 64) / 256, 256, 0, stream>>>(wo, cw, t);
    k_u<<<258, 256, 0, stream>>>(wv, bv, bo, cw, cb, t, U, cbsum, Cp);
    fused_main<<<(NB / 2 * 64) / 256, 256, 0, stream>>>(x, U, cbsum, Cp, out);
}